// Round 11
// baseline (203.936 us; speedup 1.0000x reference)
//
#include <hip/hip_runtime.h>
#include <stdint.h>

// Problem constants (B=4, S=2048, H=1024, E=8, TOP_K=2). All I/O fp32.
#define N_TOK 8192
#define H_DIM 1024
#define N_EXP 8
#define GEMM_GRID 1024   // 4 blocks/CU x 256 CU = exactly the machine's acc capacity

typedef __bf16 bf16x8 __attribute__((ext_vector_type(8)));
typedef float floatx4 __attribute__((ext_vector_type(4)));

typedef __attribute__((address_space(1))) void GV;
typedef __attribute__((address_space(3))) void LV;

static __device__ __forceinline__ unsigned short f2b(float f) {
    union { float f; unsigned int i; } v; v.f = f;
    unsigned int u = v.i;
    return (unsigned short)((u + 0x7FFFu + ((u >> 16) & 1u)) >> 16);
}

// ---------------- K1: fused router+bucket (blocks 0..1023) + W repack (1024..2047) ----------------
// Router: 8 tokens/block (2 per wave, sharing router_w loads). Bucket built via block-aggregated
// device atomics on cnt[8] (bucket order is free: each rid's output depends only on (rid, expert)).
__global__ __launch_bounds__(256) void k_front(
    const float* __restrict__ tokens,
    const float* __restrict__ router_w,
    const float* __restrict__ router_b,
    const float* __restrict__ W,
    float* __restrict__ w_arr,
    unsigned short* __restrict__ tokb,
    unsigned short* __restrict__ Bp,
    int* __restrict__ cnt, int* __restrict__ bucket)
{
    const int t = threadIdx.x;

    if (blockIdx.x >= 1024) {
        // ---- repack W[e][h][d] fp32 -> Bp[e][h>>3][d][h&7] bf16 ----
        const int idx = blockIdx.x - 1024;
        const int kg = idx & 127;
        const int e  = idx >> 7;
        const int d  = t * 4;
        const float* src = W + ((size_t)e * H_DIM + kg * 8) * H_DIM + d;
        float col[8][4];
#pragma unroll
        for (int j = 0; j < 8; ++j) {
            float4 v = *(const float4*)(src + (size_t)j * H_DIM);
            col[j][0] = v.x; col[j][1] = v.y; col[j][2] = v.z; col[j][3] = v.w;
        }
        unsigned short* dst = Bp + ((size_t)(e * 128 + kg) * H_DIM + d) * 8;
#pragma unroll
        for (int k = 0; k < 4; ++k) {
            unsigned short v[8];
#pragma unroll
            for (int j = 0; j < 8; ++j) v[j] = f2b(col[j][k]);
            *(uint4*)(dst + (size_t)k * 8) = *(uint4*)v;
        }
        return;
    }

    // ---- router: wave handles 2 tokens; block handles 8 ----
    __shared__ int bcnt[N_EXP];
    __shared__ int blist[N_EXP][16];
    if (t < N_EXP) bcnt[t] = 0;
    __syncthreads();

    const int wv = t >> 6, lane = t & 63;
    const int n0 = blockIdx.x * 8 + wv * 2;

    float x0[16], x1[16];
    const float* xp0 = tokens + (size_t)n0 * H_DIM + lane * 16;
    const float* xp1 = xp0 + H_DIM;
#pragma unroll
    for (int i = 0; i < 4; ++i) {
        float4 v = *(const float4*)(xp0 + i * 4);
        x0[i * 4 + 0] = v.x; x0[i * 4 + 1] = v.y; x0[i * 4 + 2] = v.z; x0[i * 4 + 3] = v.w;
        float4 u = *(const float4*)(xp1 + i * 4);
        x1[i * 4 + 0] = u.x; x1[i * 4 + 1] = u.y; x1[i * 4 + 2] = u.z; x1[i * 4 + 3] = u.w;
    }
    {
        unsigned short xb[16];
#pragma unroll
        for (int j = 0; j < 16; ++j) xb[j] = f2b(x0[j]);
        unsigned short* dp = tokb + (size_t)n0 * H_DIM + lane * 16;
        *(uint4*)(dp) = *(uint4*)(xb); *(uint4*)(dp + 8) = *(uint4*)(xb + 8);
#pragma unroll
        for (int j = 0; j < 16; ++j) xb[j] = f2b(x1[j]);
        dp += H_DIM;
        *(uint4*)(dp) = *(uint4*)(xb); *(uint4*)(dp + 8) = *(uint4*)(xb + 8);
    }

    float a0[N_EXP], a1[N_EXP];
#pragma unroll
    for (int e = 0; e < N_EXP; ++e) {
        const float* wp = router_w + e * H_DIM + lane * 16;
        float s0 = 0.f, s1 = 0.f;
#pragma unroll
        for (int i = 0; i < 4; ++i) {
            float4 v = *(const float4*)(wp + i * 4);
            s0 += x0[i * 4 + 0] * v.x + x0[i * 4 + 1] * v.y + x0[i * 4 + 2] * v.z + x0[i * 4 + 3] * v.w;
            s1 += x1[i * 4 + 0] * v.x + x1[i * 4 + 1] * v.y + x1[i * 4 + 2] * v.z + x1[i * 4 + 3] * v.w;
        }
        a0[e] = s0; a1[e] = s1;
    }
#pragma unroll
    for (int e = 0; e < N_EXP; ++e) {
        float p = a0[e], q = a1[e];
#pragma unroll
        for (int off = 32; off > 0; off >>= 1) { p += __shfl_xor(p, off); q += __shfl_xor(q, off); }
        a0[e] = p; a1[e] = q;
    }

    if (lane == 0) {
#pragma unroll
        for (int k = 0; k < 2; ++k) {
            const int n = n0 + k;
            float lg[N_EXP];
#pragma unroll
            for (int e = 0; e < N_EXP; ++e) lg[e] = (k ? a1[e] : a0[e]) + router_b[e];
            int e0 = 0;
#pragma unroll
            for (int e = 1; e < N_EXP; ++e) if (lg[e] > lg[e0]) e0 = e;
            int e1 = -1;
#pragma unroll
            for (int e = 0; e < N_EXP; ++e) {
                if (e == e0) continue;
                if (e1 < 0 || lg[e] > lg[e1]) e1 = e;
            }
            // collapsed weights: w0 = p0/(p0+p1) = sigmoid(l0-l1); w0+w1 = 1 exactly, so the
            // reference's /clip(sum,eps) and *(1+eps*sum) are identity at fp32 -> out = w0*y0+w1*y1.
            float w0 = 1.f / (1.f + __expf(lg[e1] - lg[e0]));
            w_arr[n * 2] = w0;
            w_arr[n * 2 + 1] = 1.f - w0;
            int s0 = atomicAdd(&bcnt[e0], 1); blist[e0][s0] = 2 * n;
            int s1 = atomicAdd(&bcnt[e1], 1); blist[e1][s1] = 2 * n + 1;
        }
    }
    __syncthreads();

    if (t < N_EXP) {
        int c = bcnt[t];
        if (c > 0) {
            int base = atomicAdd(&cnt[t], c);
            int* dst = bucket + t * N_TOK + base;
            for (int i = 0; i < c; ++i) dst[i] = blist[t][i];
        }
    }
}

// ---------------- K3: grouped GEMM, XCD-chunked, surplus K-quartered, ATOMIC-out epilogue ----------------
// T in [128,135] structurally (q=16 tiles/XCD): XCDs x < r = T&7 own a 17th tile = 8 surplus items,
// split into 4 K-quarter tasks run as PRE-tasks by blocks sblk<32 -> makespan 1.25*tau (round-10
// proven: WRITE showed the split path live, k_gemm 44.2->41.5us).
// NEW: epilogue is unsafeAtomicAdd(out + n*H + col, w*acc) -- fp32 HW atomics. w0+w1=1 makes the
// combine a pure scatter-add, so Y/Yp/k_fix/k_combine are all deleted (~70MB traffic + 2 dispatches).
// Quarter tasks atomic-add their K-partials directly; sums are exact up to fp32 add order (sub-ulp
// vs the 8.1e-2 threshold). out is zeroed by hipMemsetAsync inside kernel_launch (replay-safe).
__global__ __launch_bounds__(256, 4) void k_gemm(
    const unsigned short* __restrict__ tokb,
    const unsigned short* __restrict__ Bp,
    const int* __restrict__ cnt, const int* __restrict__ bucket,
    const float* __restrict__ w_arr, float* __restrict__ out)
{
    // As: flat [row][64], XOR-swizzled: (row, part) lives at row*64 + (part^(row&7))*8
    __shared__ __align__(16) unsigned short Asm[128 * 64];
    __shared__ __align__(16) unsigned short Bsm[8 * 128 * 8];  // chunk (kg,d) at (kg*128+d)*8
    __shared__ int rows[128];

    const int t = threadIdx.x;
    const int wv = t >> 6, lane = t & 63;
    const int w_row = wv >> 1, w_col = wv & 1;
    const int m_lane = lane & 15, quad = lane >> 4;
    const int r7 = m_lane & 7;
    const int p_sw = (lane & 7) ^ ((lane >> 3) & 7);

    int cs[N_EXP];
#pragma unroll
    for (int ee = 0; ee < N_EXP; ++ee) cs[ee] = cnt[ee];
    int T = 0;
#pragma unroll
    for (int ee = 0; ee < N_EXP; ++ee) T += (cs[ee] + 127) >> 7;

    const int x = blockIdx.x & 7;        // physical XCD (round-robin; confirmed round 3)
    const int sblk = blockIdx.x >> 3;    // 0..127 within XCD
    const int q = T >> 3, r = T & 7;     // q == 16 structurally
    const int tstart = (x < r) ? x * (q + 1) : r * (q + 1) + (x - r) * q;

    // Tasks, scalarized (rule #20). Pre-task = K-quarter of a surplus item; then the main item.
    int t0_tile, t0_nt, t0_k0, t0_k1;
    int t1_tile = -1, t1_nt = 0, t1_k0 = 0, t1_k1 = 0;
    if (x < r && sblk < 32) {
        const int oi = sblk >> 2, qk = sblk & 3;      // surplus item oi in [0,8), quarter qk
        t0_tile = tstart + 16; t0_nt = oi;
        t0_k0 = qk * 4; t0_k1 = qk * 4 + 4;
        t1_tile = tstart + (sblk >> 3); t1_nt = sblk & 7;
        t1_k0 = 0; t1_k1 = 16;
    } else {
        t0_tile = tstart + (sblk >> 3); t0_nt = sblk & 7;
        t0_k0 = 0; t0_k1 = 16;
    }

#pragma unroll 2
    for (int tk = 0; tk < 2; ++tk) {
        const int tile = tk ? t1_tile : t0_tile;
        if (tile < 0) continue;
        const int nt = tk ? t1_nt : t0_nt;
        const int k0 = tk ? t1_k0 : t0_k0;
        const int k1 = tk ? t1_k1 : t0_k1;

        int base = 0, e = 0, mt = 0;
#pragma unroll
        for (int ee = 0; ee < N_EXP; ++ee) {
            int te = (cs[ee] + 127) >> 7;
            if (tile >= base && tile < base + te) { e = ee; mt = tile - base; }
            base += te;
        }
        const int cnt_local = cs[e] - mt * 128;
        const int d0 = nt * 128;

        __syncthreads();   // previous task fully done with rows/LDS
        if (t < 128)
            rows[t] = (t < cnt_local) ? bucket[e * N_TOK + mt * 128 + t] : -1;
        __syncthreads();

        // A staging: instr i, lane l covers LDS chunk c = i*256+wv*64+l
        // -> row rr = c>>3 = i*32+wv*8+(l>>3), swizzled slot l&7 holds global part p=(l&7)^(rr&7)
        const unsigned short* aptr[4];
#pragma unroll
        for (int i = 0; i < 4; ++i) {
            int rr = i * 32 + wv * 8 + (lane >> 3);
            int rid = rows[rr];
            int tok = (rid >= 0) ? (rid >> 1) : 0;
            aptr[i] = tokb + (size_t)tok * H_DIM + p_sw * 8;
        }
        // B staging: chunk c = i*256+t -> kg' = c>>7 = i*2+(t>>7), d = t&127
        const unsigned short* bbase = Bp
            + ((size_t)(e * 128 + (t >> 7)) * H_DIM + d0 + (t & 127)) * 8;

        floatx4 acc[4][4];
#pragma unroll
        for (int i = 0; i < 4; ++i)
#pragma unroll
            for (int j = 0; j < 4; ++j) acc[i][j] = (floatx4){0.f, 0.f, 0.f, 0.f};

        for (int kt = k0; kt < k1; ++kt) {
#pragma unroll
            for (int i = 0; i < 4; ++i) {
                __builtin_amdgcn_global_load_lds(
                    (GV*)(aptr[i] + kt * 64),
                    (LV*)(&Asm[i * 2048 + wv * 512]), 16, 0, 0);
                __builtin_amdgcn_global_load_lds(
                    (GV*)(bbase + (size_t)i * 16384 + (size_t)kt * 65536),
                    (LV*)(&Bsm[i * 2048 + wv * 512]), 16, 0, 0);
            }
            __syncthreads();

#pragma unroll
            for (int s = 0; s < 2; ++s) {
                bf16x8 a[4], b[4];
#pragma unroll
                for (int i = 0; i < 4; ++i) {
                    int row = w_row * 64 + i * 16 + m_lane;
                    a[i] = *(const bf16x8*)&Asm[row * 64 + ((s * 4 + quad) ^ r7) * 8];
                }
#pragma unroll
                for (int j = 0; j < 4; ++j)
                    b[j] = *(const bf16x8*)&Bsm[((s * 4 + quad) * 128 + w_col * 64 + j * 16 + m_lane) * 8];
#pragma unroll
                for (int i = 0; i < 4; ++i)
#pragma unroll
                    for (int j = 0; j < 4; ++j)
                        acc[i][j] = __builtin_amdgcn_mfma_f32_16x16x32_bf16(a[i], b[j], acc[i][j], 0, 0, 0);
            }
            __syncthreads();
        }

        // epilogue: scatter-add w*acc into out. Actual col of acc[i][j][reg] = w_col*64 + j*16 + m_lane
        // (verified C/D layout); row = rid>>1; weight = w_arr[rid].
#pragma unroll
        for (int i = 0; i < 4; ++i) {
            const int lr_base = w_row * 64 + i * 16 + quad * 4;
#pragma unroll
            for (int reg = 0; reg < 4; ++reg) {
                const int lr = lr_base + reg;
                const int rid = rows[lr];
                if (rid >= 0) {
                    const float w = w_arr[rid];
                    float* orow = out + (size_t)(rid >> 1) * H_DIM + d0 + w_col * 64 + m_lane;
#pragma unroll
                    for (int j = 0; j < 4; ++j)
                        unsafeAtomicAdd(orow + j * 16, w * acc[i][j][reg]);
                }
            }
        }
    }
}

extern "C" void kernel_launch(void* const* d_in, const int* in_sizes, int n_in,
                              void* d_out, int out_size, void* d_ws, size_t ws_size,
                              hipStream_t stream)
{
    const float* tokens   = (const float*)d_in[0]; // fp32 [8192,1024]
    const float* router_w = (const float*)d_in[1]; // fp32 [8,1024]
    const float* router_b = (const float*)d_in[2]; // fp32 [8]
    const float* W        = (const float*)d_in[3]; // fp32 [8,1024,1024]
    float* out = (float*)d_out;                    // fp32 [8192,1024]

    char* ws = (char*)d_ws;
    int*   cnt    = (int*)(ws);                        // 32 B (zeroed below)
    float* w_arr  = (float*)(ws + 34816);              // 64 KB
    int*   bucket = (int*)(ws + 100352);               // 256 KB
    unsigned short* tokb = (unsigned short*)(ws + 362496);    // 16 MB bf16 tokens
    unsigned short* Bp   = (unsigned short*)(ws + 17139712);  // 16 MB packed bf16 W

    hipMemsetAsync(cnt, 0, N_EXP * sizeof(int), stream);
    hipMemsetAsync(out, 0, (size_t)N_TOK * H_DIM * sizeof(float), stream);  // atomics accumulate
    k_front<<<2048, 256, 0, stream>>>(tokens, router_w, router_b, W,
                                      w_arr, tokb, Bp, cnt, bucket);
    k_gemm <<<GEMM_GRID, 256, 0, stream>>>(tokb, Bp, cnt, bucket, w_arr, out);
}

// Round 12
// 177.535 us; speedup vs baseline: 1.1487x; 1.1487x over previous
//
#include <hip/hip_runtime.h>
#include <stdint.h>

// Problem constants (B=4, S=2048, H=1024, E=8, TOP_K=2). All I/O fp32.
#define N_TOK 8192
#define H_DIM 1024
#define N_EXP 8
#define GEMM_GRID 1024   // 4 blocks/CU x 256 CU = exactly the machine's acc capacity

typedef __bf16 bf16x8 __attribute__((ext_vector_type(8)));
typedef float floatx4 __attribute__((ext_vector_type(4)));

typedef __attribute__((address_space(1))) void GV;
typedef __attribute__((address_space(3))) void LV;

static __device__ __forceinline__ unsigned short f2b(float f) {
    union { float f; unsigned int i; } v; v.f = f;
    unsigned int u = v.i;
    return (unsigned short)((u + 0x7FFFu + ((u >> 16) & 1u)) >> 16);
}
static __device__ __forceinline__ float b2f(unsigned short u) {
    union { unsigned int i; float f; } v; v.i = ((unsigned int)u) << 16; return v.f;
}

// ---------------- K1: fused router+bucket (blocks 0..1023) + W repack (1024..2047) ----------------
__global__ __launch_bounds__(256) void k_front(
    const float* __restrict__ tokens,
    const float* __restrict__ router_w,
    const float* __restrict__ router_b,
    const float* __restrict__ W,
    float* __restrict__ w_arr,
    unsigned short* __restrict__ tokb,
    unsigned short* __restrict__ Bp,
    int* __restrict__ cnt, int* __restrict__ bucket,
    int* __restrict__ fix_map)
{
    const int t = threadIdx.x;

    if (blockIdx.x >= 1024) {
        // ---- repack W[e][h][d] fp32 -> Bp[e][h>>3][d][h&7] bf16 ----
        const int idx = blockIdx.x - 1024;
        const int kg = idx & 127;
        const int e  = idx >> 7;
        const int d  = t * 4;
        const float* src = W + ((size_t)e * H_DIM + kg * 8) * H_DIM + d;
        float col[8][4];
#pragma unroll
        for (int j = 0; j < 8; ++j) {
            float4 v = *(const float4*)(src + (size_t)j * H_DIM);
            col[j][0] = v.x; col[j][1] = v.y; col[j][2] = v.z; col[j][3] = v.w;
        }
        unsigned short* dst = Bp + ((size_t)(e * 128 + kg) * H_DIM + d) * 8;
#pragma unroll
        for (int k = 0; k < 4; ++k) {
            unsigned short v[8];
#pragma unroll
            for (int j = 0; j < 8; ++j) v[j] = f2b(col[j][k]);
            *(uint4*)(dst + (size_t)k * 8) = *(uint4*)v;
        }
        return;
    }

    // clear this block's 16 fix_map slots (tokens b*8..b*8+7 -> slots b*16..b*16+15)
    if (fix_map && t < 16) fix_map[blockIdx.x * 16 + t] = -1;

    // ---- router: wave handles 2 tokens; block handles 8 ----
    __shared__ int bcnt[N_EXP];
    __shared__ int blist[N_EXP][16];
    if (t < N_EXP) bcnt[t] = 0;
    __syncthreads();

    const int wv = t >> 6, lane = t & 63;
    const int n0 = blockIdx.x * 8 + wv * 2;

    float x0[16], x1[16];
    const float* xp0 = tokens + (size_t)n0 * H_DIM + lane * 16;
    const float* xp1 = xp0 + H_DIM;
#pragma unroll
    for (int i = 0; i < 4; ++i) {
        float4 v = *(const float4*)(xp0 + i * 4);
        x0[i * 4 + 0] = v.x; x0[i * 4 + 1] = v.y; x0[i * 4 + 2] = v.z; x0[i * 4 + 3] = v.w;
        float4 u = *(const float4*)(xp1 + i * 4);
        x1[i * 4 + 0] = u.x; x1[i * 4 + 1] = u.y; x1[i * 4 + 2] = u.z; x1[i * 4 + 3] = u.w;
    }
    {
        unsigned short xb[16];
#pragma unroll
        for (int j = 0; j < 16; ++j) xb[j] = f2b(x0[j]);
        unsigned short* dp = tokb + (size_t)n0 * H_DIM + lane * 16;
        *(uint4*)(dp) = *(uint4*)(xb); *(uint4*)(dp + 8) = *(uint4*)(xb + 8);
#pragma unroll
        for (int j = 0; j < 16; ++j) xb[j] = f2b(x1[j]);
        dp += H_DIM;
        *(uint4*)(dp) = *(uint4*)(xb); *(uint4*)(dp + 8) = *(uint4*)(xb + 8);
    }

    float a0[N_EXP], a1[N_EXP];
#pragma unroll
    for (int e = 0; e < N_EXP; ++e) {
        const float* wp = router_w + e * H_DIM + lane * 16;
        float s0 = 0.f, s1 = 0.f;
#pragma unroll
        for (int i = 0; i < 4; ++i) {
            float4 v = *(const float4*)(wp + i * 4);
            s0 += x0[i * 4 + 0] * v.x + x0[i * 4 + 1] * v.y + x0[i * 4 + 2] * v.z + x0[i * 4 + 3] * v.w;
            s1 += x1[i * 4 + 0] * v.x + x1[i * 4 + 1] * v.y + x1[i * 4 + 2] * v.z + x1[i * 4 + 3] * v.w;
        }
        a0[e] = s0; a1[e] = s1;
    }
#pragma unroll
    for (int e = 0; e < N_EXP; ++e) {
        float p = a0[e], q = a1[e];
#pragma unroll
        for (int off = 32; off > 0; off >>= 1) { p += __shfl_xor(p, off); q += __shfl_xor(q, off); }
        a0[e] = p; a1[e] = q;
    }

    if (lane == 0) {
#pragma unroll
        for (int k = 0; k < 2; ++k) {
            const int n = n0 + k;
            float lg[N_EXP];
#pragma unroll
            for (int e = 0; e < N_EXP; ++e) lg[e] = (k ? a1[e] : a0[e]) + router_b[e];
            int e0 = 0;
#pragma unroll
            for (int e = 1; e < N_EXP; ++e) if (lg[e] > lg[e0]) e0 = e;
            int e1 = -1;
#pragma unroll
            for (int e = 0; e < N_EXP; ++e) {
                if (e == e0) continue;
                if (e1 < 0 || lg[e] > lg[e1]) e1 = e;
            }
            // collapsed weights: w0 = p0/(p0+p1) = sigmoid(l0-l1); w0+w1=1 -> eps terms identity
            float w0 = 1.f / (1.f + __expf(lg[e1] - lg[e0]));
            w_arr[n * 2] = w0;
            w_arr[n * 2 + 1] = 1.f - w0;
            int s0 = atomicAdd(&bcnt[e0], 1); blist[e0][s0] = 2 * n;
            int s1 = atomicAdd(&bcnt[e1], 1); blist[e1][s1] = 2 * n + 1;
        }
    }
    __syncthreads();

    if (t < N_EXP) {
        int c = bcnt[t];
        if (c > 0) {
            int base = atomicAdd(&cnt[t], c);
            int* dst = bucket + t * N_TOK + base;
            for (int i = 0; i < c; ++i) dst[i] = blist[t][i];
        }
    }
}

// ---------------- K3: grouped GEMM, XCD-chunked, surplus K-quartered (round-10 proven) ----------------
// T in [128,135] (q=16 tiles/XCD): XCDs x < r = T&7 own a 17th tile = 8 surplus items, split into
// 4 K-quarter PRE-tasks on blocks sblk<32. Quarters write fp32 partials to private Yp slices;
// the qk==0 quarter records fix_map[rid] = (x<<16)|lr so k_combine can sum the slices inline
// (k_fix dispatch deleted -- round-10 lesson: every aux dispatch costs ~5-15us wall).
// split_ok==0 falls back to the round-9 two-round path (fix_map stays -1).
__global__ __launch_bounds__(256, 4) void k_gemm(
    const unsigned short* __restrict__ tokb,
    const unsigned short* __restrict__ Bp,
    const int* __restrict__ cnt, const int* __restrict__ bucket,
    unsigned short* __restrict__ Y, float* __restrict__ Yp,
    int* __restrict__ fix_map, int split_ok)
{
    __shared__ __align__(16) unsigned short Asm[128 * 64];     // XOR-swizzled rows
    __shared__ __align__(16) unsigned short Bsm[8 * 128 * 8];  // chunk (kg,d) at (kg*128+d)*8
    __shared__ int rows[128];

    const int t = threadIdx.x;
    const int wv = t >> 6, lane = t & 63;
    const int w_row = wv >> 1, w_col = wv & 1;
    const int m_lane = lane & 15, quad = lane >> 4;
    const int r7 = m_lane & 7;
    const int p_sw = (lane & 7) ^ ((lane >> 3) & 7);

    int cs[N_EXP];
#pragma unroll
    for (int ee = 0; ee < N_EXP; ++ee) cs[ee] = cnt[ee];
    int T = 0;
#pragma unroll
    for (int ee = 0; ee < N_EXP; ++ee) T += (cs[ee] + 127) >> 7;

    const int x = blockIdx.x & 7;        // physical XCD (round-robin; confirmed round 3)
    const int sblk = blockIdx.x >> 3;    // 0..127 within XCD
    const int q = T >> 3, r = T & 7;     // q == 16 structurally
    const int tstart = (x < r) ? x * (q + 1) : r * (q + 1) + (x - r) * q;
    const int tcnt   = (x < r) ? (q + 1) : q;
    const int nloc   = tcnt * 8;

    // Tasks, scalarized (rule #20).
    int t0_tile, t0_nt, t0_k0, t0_k1, t0_os;
    int t1_tile = -1, t1_nt = 0, t1_k0 = 0, t1_k1 = 0, t1_os = -1;
    if (split_ok) {
        if (x < r && sblk < 32) {
            const int oi = sblk >> 2, qk = sblk & 3;      // surplus item oi, K-quarter qk
            t0_tile = tstart + 16; t0_nt = oi;
            t0_k0 = qk * 4; t0_k1 = qk * 4 + 4;
            t0_os = (x * 8 + oi) * 4 + qk;
            t1_tile = tstart + (sblk >> 3); t1_nt = sblk & 7;
            t1_k0 = 0; t1_k1 = 16; t1_os = -1;
        } else {
            t0_tile = tstart + (sblk >> 3); t0_nt = sblk & 7;
            t0_k0 = 0; t0_k1 = 16; t0_os = -1;
        }
    } else {
        t0_tile = tstart + (sblk >> 3); t0_nt = sblk & 7;
        t0_k0 = 0; t0_k1 = 16; t0_os = -1;
        if (sblk + 128 < nloc) {                          // round-9 fallback second item
            const int l2 = sblk + 128;
            t1_tile = tstart + (l2 >> 3); t1_nt = l2 & 7;
            t1_k0 = 0; t1_k1 = 16; t1_os = -1;
        }
    }

#pragma unroll 2
    for (int tk = 0; tk < 2; ++tk) {
        const int tile = tk ? t1_tile : t0_tile;
        if (tile < 0) continue;
        const int nt = tk ? t1_nt : t0_nt;
        const int k0 = tk ? t1_k0 : t0_k0;
        const int k1 = tk ? t1_k1 : t0_k1;
        const int os = tk ? t1_os : t0_os;

        int base = 0, e = 0, mt = 0;
#pragma unroll
        for (int ee = 0; ee < N_EXP; ++ee) {
            int te = (cs[ee] + 127) >> 7;
            if (tile >= base && tile < base + te) { e = ee; mt = tile - base; }
            base += te;
        }
        const int cnt_local = cs[e] - mt * 128;
        const int d0 = nt * 128;

        __syncthreads();   // previous task fully done with rows/LDS
        if (t < 128)
            rows[t] = (t < cnt_local) ? bucket[e * N_TOK + mt * 128 + t] : -1;
        __syncthreads();

        // qk==0 quarter publishes the fix map for its 128 surplus rows
        if (os >= 0 && (os & 3) == 0 && t < 128 && rows[t] >= 0)
            fix_map[rows[t]] = (x << 16) | t;

        const unsigned short* aptr[4];
#pragma unroll
        for (int i = 0; i < 4; ++i) {
            int rr = i * 32 + wv * 8 + (lane >> 3);
            int rid = rows[rr];
            int tok = (rid >= 0) ? (rid >> 1) : 0;
            aptr[i] = tokb + (size_t)tok * H_DIM + p_sw * 8;
        }
        const unsigned short* bbase = Bp
            + ((size_t)(e * 128 + (t >> 7)) * H_DIM + d0 + (t & 127)) * 8;

        floatx4 acc[4][4];
#pragma unroll
        for (int i = 0; i < 4; ++i)
#pragma unroll
            for (int j = 0; j < 4; ++j) acc[i][j] = (floatx4){0.f, 0.f, 0.f, 0.f};

        for (int kt = k0; kt < k1; ++kt) {
#pragma unroll
            for (int i = 0; i < 4; ++i) {
                __builtin_amdgcn_global_load_lds(
                    (GV*)(aptr[i] + kt * 64),
                    (LV*)(&Asm[i * 2048 + wv * 512]), 16, 0, 0);
                __builtin_amdgcn_global_load_lds(
                    (GV*)(bbase + (size_t)i * 16384 + (size_t)kt * 65536),
                    (LV*)(&Bsm[i * 2048 + wv * 512]), 16, 0, 0);
            }
            __syncthreads();

#pragma unroll
            for (int s = 0; s < 2; ++s) {
                bf16x8 a[4], b[4];
#pragma unroll
                for (int i = 0; i < 4; ++i) {
                    int row = w_row * 64 + i * 16 + m_lane;
                    a[i] = *(const bf16x8*)&Asm[row * 64 + ((s * 4 + quad) ^ r7) * 8];
                }
#pragma unroll
                for (int j = 0; j < 4; ++j)
                    b[j] = *(const bf16x8*)&Bsm[((s * 4 + quad) * 128 + w_col * 64 + j * 16 + m_lane) * 8];
#pragma unroll
                for (int i = 0; i < 4; ++i)
#pragma unroll
                    for (int j = 0; j < 4; ++j)
                        acc[i][j] = __builtin_amdgcn_mfma_f32_16x16x32_bf16(a[i], b[j], acc[i][j], 0, 0, 0);
            }
            __syncthreads();
        }

        if (os < 0) {
            // full item: bf16 Y stores, permuted-within-segment layout
#pragma unroll
            for (int i = 0; i < 4; ++i) {
                const int lr_base = w_row * 64 + i * 16 + quad * 4;
#pragma unroll
                for (int reg = 0; reg < 4; ++reg) {
                    const int lr = lr_base + reg;
                    const int rid = rows[lr];
                    if (rid >= 0) {
                        unsigned short v[4];
#pragma unroll
                        for (int j = 0; j < 4; ++j) v[j] = f2b(acc[i][j][reg]);
                        *(uint2*)(Y + (size_t)rid * H_DIM + d0 + w_col * 64 + m_lane * 4) = *(uint2*)v;
                    }
                }
            }
        } else {
            // quarter task: fp32 partial to private Yp slice (same stored-col layout)
            float* dst = Yp + (size_t)os * 16384;
#pragma unroll
            for (int i = 0; i < 4; ++i) {
#pragma unroll
                for (int reg = 0; reg < 4; ++reg) {
                    const int lr = w_row * 64 + i * 16 + quad * 4 + reg;
                    float4 v = make_float4(acc[i][0][reg], acc[i][1][reg],
                                           acc[i][2][reg], acc[i][3][reg]);
                    *(float4*)(dst + lr * 128 + w_col * 64 + m_lane * 4) = v;
                }
            }
        }
    }
}

// ---------------- K4: combine via LDS de-permute + inline fix of surplus rows ----------------
__global__ __launch_bounds__(256) void k_combine(
    const unsigned short* __restrict__ Y, const float* __restrict__ w_arr,
    const float* __restrict__ Yp, const int* __restrict__ fix_map,
    float* __restrict__ out)
{
    __shared__ __align__(16) unsigned short Ys[4 * H_DIM];
    const int t = threadIdx.x;
    const int b = blockIdx.x;
    const int wv = t >> 6, lane = t & 63;
    const unsigned short* src = Y + (size_t)b * 4 * H_DIM;
#pragma unroll
    for (int r = 0; r < 2; ++r) {
        __builtin_amdgcn_global_load_lds(
            (GV*)(src + (size_t)r * 2048 + wv * 512 + lane * 8),
            (LV*)(&Ys[r * 2048 + wv * 512]), 16, 0, 0);
    }
    __syncthreads();

    const int tok = t >> 7;
    const int n = 2 * b + tok;
    const int d0 = (t & 127) * 8;
    const int seg = d0 >> 7;
    const int dseg = d0 & 127;
    const int wc = dseg >> 6;
    const int j  = (dseg >> 4) & 3;
    const int m0 = dseg & 15;
    const int tok2H = tok * 2 * H_DIM;
    const float w0 = w_arr[2 * n], w1 = w_arr[2 * n + 1];

    const int rid0 = 4 * b + 2 * tok;
    const int fm0 = fix_map ? fix_map[rid0] : -1;
    const int fm1 = fix_map ? fix_map[rid0 + 1] : -1;

    float v0[8], v1[8];
    if (fm0 < 0) {
#pragma unroll
        for (int k = 0; k < 8; ++k)
            v0[k] = b2f(Ys[tok2H + seg * 128 + wc * 64 + (m0 + k) * 4 + j]);
    } else {
        const float* yb = Yp + (size_t)(((fm0 >> 16) * 8 + seg) * 4) * 16384
                             + (fm0 & 0xFFFF) * 128;
#pragma unroll
        for (int k = 0; k < 8; ++k) {
            int sl = wc * 64 + (m0 + k) * 4 + j;
            v0[k] = yb[sl] + yb[16384 + sl] + yb[32768 + sl] + yb[49152 + sl];
        }
    }
    if (fm1 < 0) {
#pragma unroll
        for (int k = 0; k < 8; ++k)
            v1[k] = b2f(Ys[tok2H + H_DIM + seg * 128 + wc * 64 + (m0 + k) * 4 + j]);
    } else {
        const float* yb = Yp + (size_t)(((fm1 >> 16) * 8 + seg) * 4) * 16384
                             + (fm1 & 0xFFFF) * 128;
#pragma unroll
        for (int k = 0; k < 8; ++k) {
            int sl = wc * 64 + (m0 + k) * 4 + j;
            v1[k] = yb[sl] + yb[16384 + sl] + yb[32768 + sl] + yb[49152 + sl];
        }
    }

    float o[8];
#pragma unroll
    for (int k = 0; k < 8; ++k) o[k] = w0 * v0[k] + w1 * v1[k];
    float4* op = (float4*)(out + (size_t)n * H_DIM + d0);
    op[0] = make_float4(o[0], o[1], o[2], o[3]);
    op[1] = make_float4(o[4], o[5], o[6], o[7]);
}

extern "C" void kernel_launch(void* const* d_in, const int* in_sizes, int n_in,
                              void* d_out, int out_size, void* d_ws, size_t ws_size,
                              hipStream_t stream)
{
    const float* tokens   = (const float*)d_in[0]; // fp32 [8192,1024]
    const float* router_w = (const float*)d_in[1]; // fp32 [8,1024]
    const float* router_b = (const float*)d_in[2]; // fp32 [8]
    const float* W        = (const float*)d_in[3]; // fp32 [8,1024,1024]
    float* out = (float*)d_out;                    // fp32 [8192,1024]

    char* ws = (char*)d_ws;
    int*   cnt    = (int*)(ws);                        // 32 B (zeroed below)
    float* w_arr  = (float*)(ws + 34816);              // 64 KB
    int*   bucket = (int*)(ws + 100352);               // 256 KB
    unsigned short* tokb = (unsigned short*)(ws + 362496);    // 16 MB bf16 tokens
    unsigned short* Bp   = (unsigned short*)(ws + 17139712);  // 16 MB packed bf16 W
    unsigned short* Y    = (unsigned short*)(ws + 33916928);  // 32 MB bf16 slot outputs [ends 67,471,360]
    int*   fix_map = (int*)(ws + 67471360);            // 64 KB slot->Yp map [ends 67,536,896]
    float* Yp      = (float*)(ws + 67536896);          // 14.7 MB fp32 quarter-partials [ends 82,216,960]

    const int split_ok = (ws_size >= 82216960ull) ? 1 : 0;
    int* fm = split_ok ? fix_map : (int*)nullptr;

    hipMemsetAsync(cnt, 0, N_EXP * sizeof(int), stream);
    k_front  <<<2048, 256, 0, stream>>>(tokens, router_w, router_b, W,
                                        w_arr, tokb, Bp, cnt, bucket, fm);
    k_gemm   <<<GEMM_GRID, 256, 0, stream>>>(tokb, Bp, cnt, bucket, Y, Yp, fm, split_ok);
    k_combine<<<N_TOK * (H_DIM / 8) / 256, 256, 0, stream>>>(Y, w_arr, Yp, fm, out);
}